// Round 3
// baseline (3864.444 us; speedup 1.0000x reference)
//
#include <hip/hip_runtime.h>
#include <stdint.h>

typedef __attribute__((ext_vector_type(8))) __bf16 bf16x8;
typedef __attribute__((ext_vector_type(4))) float f32x4;

#define DEVI static __device__ __forceinline__
#define SENT 0xFFFFFFFFu

DEVI bf16x8 bzero8(){ bf16x8 r;
#pragma unroll
  for (int i=0;i<8;++i) r[i]=(__bf16)0.0f; return r; }

DEVI bf16x8 ld8(const __bf16* p){ return *(const bf16x8*)p; }
DEVI void st8(__bf16* p, bf16x8 v){ *(bf16x8*)p = v; }

DEVI f32x4 MFMA(bf16x8 a, bf16x8 b, f32x4 c){
  return __builtin_amdgcn_mfma_f32_16x16x32_bf16(a, b, c, 0, 0, 0);
}

DEVI float sigf(float x){ return 1.0f/(1.0f+__expf(-x)); }

// ---- coherent (cross-XCD) relaxed atomics: bypass L2, NO fences ----
DEVI unsigned ald(const unsigned* p){ return __hip_atomic_load(p, __ATOMIC_RELAXED, __HIP_MEMORY_SCOPE_AGENT); }
DEVI void ast(unsigned* p, unsigned v){ __hip_atomic_store(p, v, __ATOMIC_RELAXED, __HIP_MEMORY_SCOPE_AGENT); }

DEVI bf16x8 ald8(const __bf16* p){
  const unsigned* q = (const unsigned*)p;
  union { bf16x8 v; unsigned u[4]; } r;
  r.u[0]=ald(q+0); r.u[1]=ald(q+1); r.u[2]=ald(q+2); r.u[3]=ald(q+3);
  return r.v;
}
DEVI bool sent8(bf16x8 v){
  union { bf16x8 b; unsigned u[4]; } x; x.b=v;
  return (x.u[0]==SENT)|(x.u[1]==SENT)|(x.u[2]==SENT)|(x.u[3]==SENT);
}
DEVI unsigned packbf(float a, float b){
  union { __bf16 h[2]; unsigned u; } x; x.h[0]=(__bf16)a; x.h[1]=(__bf16)b; return x.u;
}
DEVI float bflo(unsigned u){ return __builtin_bit_cast(float, u<<16); }
DEVI float bfhi(unsigned u){ return __builtin_bit_cast(float, u & 0xffff0000u); }

// ---- flag barrier (init-only use now) ----
DEVI void flagbar(unsigned* slots, int nblk, int bk, unsigned ep){
  __syncthreads();
  asm volatile("" ::: "memory");
  if (threadIdx.x == 0) ast(slots + (size_t)bk*16, ep);
  if ((int)threadIdx.x < nblk){
    const unsigned* sp = slots + (size_t)threadIdx.x*16;
    while (ald(sp) < ep) __builtin_amdgcn_s_sleep(1);
  }
  asm volatile("" ::: "memory");
  __syncthreads();
}

// ---------------- packing ----------------
DEVI void packGroup(const float* W, int Nsrc, int Kreal, int NT, __bf16* dst, long g){
  int kt = (int)(g / (NT*64));
  int rem = (int)(g % (NT*64));
  int nt = rem >> 6, ln = rem & 63;
  int row = nt*16 + (ln & 15);
  int col = kt*32 + ((ln >> 4) << 3);
  bf16x8 v = bzero8();
  if (row < Nsrc){
#pragma unroll
    for (int j=0;j<8;++j){ int c = col + j; if (c < Kreal) v[j] = (__bf16)W[(long)row*Kreal + c]; }
  }
  st8(dst + g*8, v);
}

DEVI void packGroupCat(const float* Wih, const float* Whh, __bf16* dst, long g){
  int kt = (int)(g / (128*64));
  int rem = (int)(g % (128*64));
  int nt = rem >> 6, ln = rem & 63;
  int prow = nt*16 + (ln & 15);
  int src = (prow & 3)*512 + (prow >> 2);
  int col = kt*32 + ((ln >> 4) << 3);
  bf16x8 v;
  if (col < 32){
#pragma unroll
    for (int j=0;j<8;++j) v[j] = (__bf16)Wih[(long)src*32 + col + j];
  } else {
#pragma unroll
    for (int j=0;j<8;++j) v[j] = (__bf16)Whh[(long)src*512 + (col-32) + j];
  }
  st8(dst + g*8, v);
}

// zero flag slots + sentinel the decoder comm buffers
__global__ void initK(unsigned* bar, unsigned* hb, unsigned* ctx, unsigned* xb){
  int g = blockIdx.x*256 + threadIdx.x;
  if (g < 3072){ bar[g] = 0u; return; }
  g -= 3072;
  if (g < 6144){ hb[2048 + g] = SENT; return; }   // HB bufs 1..3 (buf0 = h0b from pyramid)
  g -= 6144;
  if (g < 8192){ ctx[g] = SENT; return; }         // CTXB all 4 bufs
  g -= 8192;
  if (g < 4096){ xb[g] = SENT; return; }          // XB all 4 bufs
}

__global__ void packSmallK(const float* __restrict__ xs, const float* __restrict__ eWih,
    const float* __restrict__ eWhh, const float* __restrict__ ebih, const float* __restrict__ ebhh,
    const float* __restrict__ attnW, const float* __restrict__ combW,
    __bf16* __restrict__ xsb, __bf16* __restrict__ wcatp, float* __restrict__ biasc,
    __bf16* __restrict__ attnp, __bf16* __restrict__ combp)
{
  long g = (long)blockIdx.x*blockDim.x + threadIdx.x;
  const long nWcat = 17L*128*64;
  const long nXs   = 92160;
  const long nBias = 2048;
  const long nAttn = 33L*2*64;
  const long nComb = 33L*32*64;
  if (g < nWcat){ packGroupCat(eWih, eWhh, wcatp, g); return; }
  g -= nWcat;
  if (g < nXs){
    const float* s = xs + g*8; bf16x8 v;
#pragma unroll
    for (int j=0;j<8;++j) v[j] = (__bf16)s[j];
    st8(xsb + g*8, v); return;
  }
  g -= nXs;
  if (g < nBias){ int src = ((int)g & 3)*512 + ((int)g >> 2); biasc[g] = ebih[src] + ebhh[src]; return; }
  g -= nBias;
  if (g < nAttn){ packGroup(attnW, 30, 1032, 2, attnp, g); return; }
  g -= nAttn;
  if (g < nComb){ packGroup(combW, 512, 1032, 32, combp, g); return; }
}

__global__ void packPencK(const float* __restrict__ Wf, const float* __restrict__ Wb,
    const float* __restrict__ bihf, const float* __restrict__ bhhf,
    const float* __restrict__ bihb, const float* __restrict__ bhhb,
    __bf16* __restrict__ pf, __bf16* __restrict__ pb, float* __restrict__ bsum)
{
  long g = (long)blockIdx.x*blockDim.x + threadIdx.x;
  const long nW = 64L*128*64;
  if (g < nW){ packGroup(Wf, 2048, 2048, 128, pf, g); return; }
  g -= nW;
  if (g < nW){ packGroup(Wb, 2048, 2048, 128, pb, g); return; }
  g -= nW;
  if (g < 2048){ bsum[g] = bihf[g] + bhhf[g]; return; }
  g -= 2048;
  if (g < 2048){ bsum[2048+g] = bihb[g] + bhhb[g]; return; }
}

// ---------------- encoder step ----------------
__global__ __launch_bounds__(256, 1) void encStepK(
    const __bf16* __restrict__ xsb,
    __bf16* __restrict__ henc,
    float* __restrict__ cenc,
    const __bf16* __restrict__ wcatp,
    const float* __restrict__ biasc,
    const int* __restrict__ xlen,
    __bf16* __restrict__ ctx,
    int t)
{
  __shared__ float glds[64][260];
  const int tid = threadIdx.x;
  const int w = tid >> 6, ln = tid & 63;
  const int m0 = blockIdx.x * 64;
  const int nb = blockIdx.y;
  f32x4 acc[16];
#pragma unroll
  for (int i=0;i<16;++i) acc[i] = (f32x4){0.f,0.f,0.f,0.f};

  const int arow = m0 + w*16 + (ln & 15);
  const int kc = (ln >> 4) << 3;
  const int ktEnd = (t == 0) ? 1 : 17;
  for (int kt = 0; kt < ktEnd; ++kt){
    bf16x8 a;
    if (kt == 0) a = ld8(xsb + ((long)t*1920 + arow)*32 + kc);
    else         a = ld8(henc + (long)arow*512 + (kt-1)*32 + kc);
    const __bf16* bp = wcatp + (((long)kt*128 + nb*16)*64 + ln)*8;
#pragma unroll
    for (int n2 = 0; n2 < 16; ++n2){
      bf16x8 b = ld8(bp + (long)n2*512);
      acc[n2] = MFMA(a, b, acc[n2]);
    }
  }
  const int r4 = (ln >> 4) << 2;
#pragma unroll
  for (int n2 = 0; n2 < 16; ++n2){
#pragma unroll
    for (int r = 0; r < 4; ++r)
      glds[w*16 + r4 + r][n2*16 + (ln & 15)] = acc[n2][r];
  }
  __syncthreads();
  for (int it = 0; it < 16; ++it){
    int idx = tid + it*256;
    int mrow = idx >> 6, hcl = idx & 63;
    int n = m0 + mrow;
    int hcg = nb*64 + hcl;
    float ig = glds[mrow][hcl*4+0] + biasc[nb*256 + hcl*4+0];
    float fg = glds[mrow][hcl*4+1] + biasc[nb*256 + hcl*4+1];
    float gg = glds[mrow][hcl*4+2] + biasc[nb*256 + hcl*4+2];
    float og = glds[mrow][hcl*4+3] + biasc[nb*256 + hcl*4+3];
    float c_old = (t == 0) ? 0.0f : cenc[(long)n*512 + hcg];
    float cn = sigf(fg)*c_old + sigf(ig)*tanhf(gg);
    float h  = sigf(og)*tanhf(cn);
    cenc[(long)n*512 + hcg] = cn;
    henc[(long)n*512 + hcg] = (__bf16)h;
    if (xlen[n] - 1 == t){
      ctx[(long)n*1024 + hcg]       = (__bf16)h;
      ctx[(long)n*1024 + 512 + hcg] = (__bf16)cn;
    }
  }
}

// ---------------- pyramid input GEMM ----------------
__global__ __launch_bounds__(1024) void pencInK(
   const __bf16* __restrict__ inb,
   const __bf16* __restrict__ wpf, const __bf16* __restrict__ wpb,
   const float* __restrict__ bsum,
   float* __restrict__ xpf, float* __restrict__ xpb,
   int M)
{
  const int tid = threadIdx.x, ln = tid & 63, wv = tid >> 6;
  const int rg = wv >> 2, cg = wv & 3;
  const int dir = blockIdx.z;
  const int m0 = blockIdx.x*64 + rg*16;
  const int nb = blockIdx.y;
  const __bf16* wp = dir ? wpb : wpf;
  float* xp = dir ? xpb : xpf;
  const float* bs = bsum + dir*2048;
  f32x4 acc[4];
#pragma unroll
  for (int i=0;i<4;++i) acc[i] = (f32x4){0.f,0.f,0.f,0.f};
  const int arow = m0 + (ln & 15);
  const int kc = (ln >> 4) << 3;
  const bool aok = arow < M;
  for (int kt = 0; kt < 64; ++kt){
    bf16x8 a = aok ? ld8(inb + (long)arow*2048 + kt*32 + kc) : bzero8();
    const __bf16* bp = wp + (((long)kt*128 + nb*16 + cg*4)*64 + ln)*8;
#pragma unroll
    for (int q = 0; q < 4; ++q){
      bf16x8 b = ld8(bp + (long)q*512);
      acc[q] = MFMA(a, b, acc[q]);
    }
  }
  const int r4 = (ln >> 4) << 2;
#pragma unroll
  for (int q = 0; q < 4; ++q){
    int col = (nb*16 + cg*4 + q)*16 + (ln & 15);
#pragma unroll
    for (int r = 0; r < 4; ++r){
      int rowo = m0 + r4 + r;
      if (rowo < M) xp[(long)rowo*2048 + col] = acc[q][r] + bs[col];
    }
  }
}

// ---------------- pyramid recurrence: persistent, data-poll h exchange ----------------
// hbuf: [2dir][4buf][4b][512] bf16, sentinel protocol
__global__ __launch_bounds__(256, 1) void pyrRecK(
  const float* __restrict__ WhhF, const float* __restrict__ WhhB,
  const float* __restrict__ xpf, const float* __restrict__ xpb,
  __bf16* __restrict__ hbuf,
  __bf16* __restrict__ outb,
  float* __restrict__ outf,
  float* __restrict__ h0f, __bf16* __restrict__ h0b,
  unsigned* __restrict__ slotsF, unsigned* __restrict__ slotsB,
  int T, int isLast)
{
  __shared__ __align__(16) __bf16 WL[128*512];
  __shared__ float glds[4][4][32];
  const int tid = threadIdx.x, ln = tid & 63, w = tid >> 6;
  const int bk = blockIdx.x;
  const int dir = bk >> 4, blk = bk & 15;
  const int hc0 = blk * 32;
  const float* Whh = dir ? WhhB : WhhF;
  const float* xp  = dir ? xpb : xpf;
  unsigned* slots = dir ? slotsB : slotsF;
  unsigned* hbu = (unsigned*)hbuf;

  for (int it = 0; it < 32; ++it){
    int g = it*256 + tid;
    int rho = g >> 6, c8 = g & 63;
    int gate = rho >> 5, hcl = rho & 31;
    const float* src = Whh + ((long)(gate*512 + hc0 + hcl))*512 + c8*8;
    bf16x8 v;
#pragma unroll
    for (int j=0;j<8;++j) v[j] = (__bf16)src[j];
    int off = (rho*1024 + c8*16) ^ ((rho & 7) << 4);
    st8((__bf16*)((char*)WL + off), v);
  }
  // init own h cols: buf0 = 0, bufs 1..3 = sentinel
  if (tid < 128 && !(tid & 1)){
    int b = tid >> 5, hcl = tid & 31;
    int base = (hc0 + hcl) >> 1;
#pragma unroll
    for (int bu = 0; bu < 4; ++bu)
      ast(hbu + ((size_t)(dir*4 + bu)*4 + b)*256 + base, bu == 0 ? 0u : SENT);
  }
  flagbar(slots, 16, blk, 1);

  float cv = 0.0f;
  const int arow = ln & 15;
  const int kc = (ln >> 4) << 3;
  const int rho0 = w*32 + (ln & 15);
  const int rho1 = rho0 + 16;
  for (int t = 0; t < T; ++t){
    int cur = t & 3, nxt = (t+1) & 3, clr = (t+2) & 3;
    int pos = dir ? (T-1-t) : t;
    // prefetch cell inputs (independent of h)
    float x0=0.f, x1=0.f, x2=0.f, x3=0.f;
    if (tid < 128){
      const float* xr = xp + ((long)((tid>>5)*T + pos))*2048 + hc0 + (tid & 31);
      x0 = xr[0]; x1 = xr[512]; x2 = xr[1024]; x3 = xr[1536];
    }
    // re-sentinel buffer t+2 (own cols); drained by next __syncthreads before produce
    if (tid < 128 && !(tid & 1)){
      int b = tid >> 5, hcl = tid & 31;
      ast(hbu + ((size_t)(dir*4 + clr)*4 + b)*256 + ((hc0 + hcl) >> 1), SENT);
    }
    // poll h(t) fragments straight into registers
    bf16x8 af[16];
    if (arow < 4){
      const __bf16* hsrc = hbuf + ((size_t)(dir*4 + cur)*4 + arow)*512 + kc;
#pragma unroll
      for (int kt = 0; kt < 16; ++kt) af[kt] = ald8(hsrc + kt*32);
      bool again = true;
      while (again){ again = false;
#pragma unroll
        for (int kt = 0; kt < 16; ++kt)
          if (sent8(af[kt])){ af[kt] = ald8(hsrc + kt*32); again = true; }
      }
    } else {
#pragma unroll
      for (int kt = 0; kt < 16; ++kt) af[kt] = bzero8();
    }
    f32x4 a0 = {0.f,0.f,0.f,0.f}, a1 = {0.f,0.f,0.f,0.f};
#pragma unroll
    for (int kt = 0; kt < 16; ++kt){
      int k2 = (kt*32 + kc)*2;
      bf16x8 b0 = ld8((__bf16*)((char*)WL + ((rho0*1024 + k2) ^ ((rho0 & 7) << 4))));
      bf16x8 b1 = ld8((__bf16*)((char*)WL + ((rho1*1024 + k2) ^ ((rho1 & 7) << 4))));
      a0 = MFMA(af[kt], b0, a0);
      a1 = MFMA(af[kt], b1, a1);
    }
    __syncthreads();
    if (ln < 16){
#pragma unroll
      for (int r=0;r<4;++r){ glds[w][r][ln] = a0[r]; glds[w][r][16+ln] = a1[r]; }
    }
    __syncthreads();
    if (tid < 128){
      int b = tid >> 5, hcl = tid & 31, hcg = hc0 + hcl;
      float ig = glds[0][b][hcl] + x0;
      float fg = glds[1][b][hcl] + x1;
      float gg = glds[2][b][hcl] + x2;
      float og = glds[3][b][hcl] + x3;
      cv = sigf(fg)*cv + sigf(ig)*tanhf(gg);
      float h = sigf(og)*tanhf(cv);
      float hn = __shfl_down(h, 1);
      if (!(hcl & 1))
        ast(hbu + ((size_t)(dir*4 + nxt)*4 + b)*256 + (hcg >> 1), packbf(h, hn));
      if (!isLast){
        outb[((long)(b*T + pos))*1024 + dir*512 + hcg] = (__bf16)h;
      } else {
        outf[((long)(b*T + pos))*1024 + dir*512 + hcg] = h;
        if (t == T-1){
          h0f[b*1024 + dir*512 + hcg] = h;
          h0b[b*1024 + dir*512 + hcg] = (__bf16)h;
        }
      }
    }
  }
}

// ---------------- decoder: persistent, 64 blocks, data-poll, no barriers ----------------
DEVI bf16x8 dfrag(const __bf16* base, const __bf16* inp, int row, int kt, int kc, int stride){
  if (row >= 4) return bzero8();
  int k = kt*32 + kc;
  if (k == 0) return ld8(inp + row*8);
  int off = k - 8;
  return (off < 1024) ? ld8(base + row*stride + off) : bzero8();
}

__global__ __launch_bounds__(256, 1) void decoderK(
  const float* __restrict__ gWih,   // [3072][512]
  const float* __restrict__ gWhh,   // [3072][1024]
  const float* __restrict__ gbih, const float* __restrict__ gbhh,
  const float* __restrict__ combBias, const float* __restrict__ attnBias,
  const float* __restrict__ outW, const float* __restrict__ outBias,
  const __bf16* __restrict__ attnP, const __bf16* __restrict__ combP,
  const float* __restrict__ encOut,
  const float* __restrict__ h0f,
  __bf16* __restrict__ HB,          // [4buf][4][1024]
  __bf16* __restrict__ CTXB,        // [4buf][4][1024]
  __bf16* __restrict__ XB,          // [4buf][4][512]
  float* __restrict__ dout)
{
  __shared__ __align__(16) __bf16 WghL[48*1024];
  __shared__ __align__(16) __bf16 hL[4*1024];
  __shared__ __align__(16) __bf16 ctxvL[4][1056];
  __shared__ __align__(16) __bf16 outWL[8*1024];
  __shared__ __bf16 encOutL[4][30][16];
  __shared__ __align__(16) __bf16 inpL[32];
  __shared__ float awL[4][30];
  __shared__ float redL[4][8];
  __shared__ float ghL[2][3][4][16];
  __shared__ float combL[4][4][16];
  __shared__ float rzL[2][4][16];
  __shared__ float inL[4][16], hnL[4][16];

  const int tid = threadIdx.x, ln = tid & 63, w = tid >> 6;
  const int bk = blockIdx.x;
  const int hc0 = bk * 16;
  unsigned* HBu = (unsigned*)HB;
  unsigned* CTXu = (unsigned*)CTXB;
  unsigned* XBu = (unsigned*)XB;

  // WghL preload (f32 -> bf16, XOR swizzled)
  for (int it = 0; it < 24; ++it){
    int g = it*256 + tid;
    int rho = g >> 7, c8 = g & 127;
    int gate = rho >> 4, r16 = rho & 15;
    const float* s = gWhh + ((long)(gate*1024 + hc0 + r16))*1024 + c8*8;
    bf16x8 v;
#pragma unroll
    for (int j=0;j<8;++j) v[j] = (__bf16)s[j];
    st8((__bf16*)((char*)WghL + ((rho*2048 + c8*16) ^ ((rho & 7) << 4))), v);
  }
  // outW -> LDS bf16
  for (int it = 0; it < 32; ++it){
    int g = it*256 + tid;
    outWL[g] = (__bf16)outW[g];
  }
  for (int idx = tid; idx < 1920; idx += 256){
    int b = idx/480, rem = idx%480;
    int t2 = rem >> 4, dl = rem & 15;
    encOutL[b][t2][dl] = (__bf16)encOut[((long)b*30 + t2)*1024 + hc0 + dl];
  }
  // register-resident B operands
  const int row = ln & 15, kc = (ln >> 4) << 3;
  bf16x8 attF[33];
  if (w < 2){
#pragma unroll
    for (int kt = 0; kt < 33; ++kt)
      attF[kt] = ld8(attnP + (((size_t)kt*2 + w)*64 + ln)*8);
  }
  bf16x8 giF[16];
  if (w < 3){
#pragma unroll
    for (int kt = 0; kt < 16; ++kt){
      const float* s = gWih + ((long)(w*1024 + hc0 + row))*512 + kt*32 + kc;
      bf16x8 v;
#pragma unroll
      for (int j=0;j<8;++j) v[j] = (__bf16)s[j];
      giF[kt] = v;
    }
  }
  const int kt0c = (w == 0) ? 0 : (w*8 + 1);
  const int nkt = (w == 0) ? 9 : 8;
  bf16x8 combF[9];
  if (bk < 32){
#pragma unroll
    for (int i = 0; i < 9; ++i)
      combF[i] = (i < nkt) ? ld8(combP + (((size_t)(kt0c+i)*32 + bk)*64 + ln)*8) : bzero8();
  }
  float hold = 0.f;
  if (tid < 64) hold = h0f[(tid>>4)*1024 + hc0 + (tid & 15)];
  __syncthreads();

  for (int s = 0; s <= 32; ++s){
    int cur = s & 3, nxt = (s+1) & 3, clr = (s+2) & 3;
    // re-sentinel buffers for step s+2 (own cols)
    if (tid < 64 && !(tid & 1)){
      int b = tid >> 4, l = tid & 15;
      ast(HBu  + ((size_t)clr*4 + b)*512 + ((hc0 + l) >> 1), SENT);
      ast(CTXu + ((size_t)clr*4 + b)*512 + ((hc0 + l) >> 1), SENT);
      if (bk < 32) ast(XBu + ((size_t)clr*4 + b)*256 + ((bk*16 + l) >> 1), SENT);
    }
    // poll h(s) -> hL
    {
      const unsigned* hq = HBu + (size_t)cur*2048 + tid*8;
      unsigned v[8];
#pragma unroll
      for (int i=0;i<8;++i) v[i] = ald(hq+i);
      bool again = true;
      while (again){ again = false;
#pragma unroll
        for (int i=0;i<8;++i) if (v[i]==SENT){ v[i] = ald(hq+i); again = true; }
      }
      unsigned* hl = (unsigned*)hL;
#pragma unroll
      for (int i=0;i<8;++i) hl[tid*8+i] = v[i];
    }
    __syncthreads();
    if (s == 0){
      if (tid < 32) inpL[tid] = (__bf16)0.0f;
      __syncthreads();
    } else {
      int o = tid >> 3, sl = tid & 7;
      int b = o >> 3, l = o & 7;
      const unsigned* hlp = (const unsigned*)hL + b*512 + sl*64;
      const unsigned* wlp = (const unsigned*)outWL + l*512 + sl*64;
      float p = 0.f;
      for (int kk = 0; kk < 64; ++kk){
        unsigned u = hlp[kk], t2 = wlp[kk];
        p += bflo(u)*bflo(t2) + bfhi(u)*bfhi(t2);
      }
      p += __shfl_down(p, 4);
      p += __shfl_down(p, 2);
      p += __shfl_down(p, 1);
      if (sl == 0) redL[b][l] = p + outBias[l];
      __syncthreads();
      if (tid < 4){
        float m = redL[tid][0];
        for (int l2=1;l2<8;++l2) m = fmaxf(m, redL[tid][l2]);
        float sum = 0.f;
        for (int l2=0;l2<8;++l2) sum += __expf(redL[tid][l2]-m);
        float lse = m + __logf(sum);
        for (int l2=0;l2<8;++l2){
          float lp = redL[tid][l2] - lse;
          inpL[tid*8 + l2] = (__bf16)lp;
          if (bk == 0) dout[((long)tid*32 + (s-1))*8 + l2] = lp;
        }
      }
      __syncthreads();
    }
    if (s == 32) break;

    // P1: w0/w1 attn logits (reg B), w2/w3 gh partials (LDS B, K-split)
    if (w < 2){
      f32x4 acc = {0.f,0.f,0.f,0.f};
#pragma unroll
      for (int kt = 0; kt < 33; ++kt){
        bf16x8 a = dfrag(hL, inpL, row, kt, kc, 1024);
        acc = MFMA(a, attF[kt], acc);
      }
      if (ln < 16 && w*16 + ln < 30){
        int col = w*16 + ln;
#pragma unroll
        for (int r=0;r<4;++r) awL[r][col] = acc[r] + attnBias[col];
      }
    } else {
      int pw = w - 2;
      f32x4 g0 = {0.f,0.f,0.f,0.f}, g1 = g0, g2 = g0;
#pragma unroll
      for (int kt = 0; kt < 16; ++kt){
        int k = (pw*16 + kt)*32 + kc;
        bf16x8 a = (row < 4) ? ld8(hL + row*1024 + k) : bzero8();
        bf16x8 b0 = ld8((__bf16*)((char*)WghL + (((0*16+row)*2048 + k*2) ^ ((row & 7) << 4))));
        g0 = MFMA(a, b0, g0);
        int rho1 = 16 + row;
        bf16x8 b1 = ld8((__bf16*)((char*)WghL + ((rho1*2048 + k*2) ^ ((rho1 & 7) << 4))));
        g1 = MFMA(a, b1, g1);
        int rho2 = 32 + row;
        bf16x8 b2 = ld8((__bf16*)((char*)WghL + ((rho2*2048 + k*2) ^ ((rho2 & 7) << 4))));
        g2 = MFMA(a, b2, g2);
      }
      if (ln < 16){
#pragma unroll
        for (int r=0;r<4;++r){
          ghL[pw][0][r][ln] = g0[r];
          ghL[pw][1][r][ln] = g1[r];
          ghL[pw][2][r][ln] = g2[r];
        }
      }
    }
    __syncthreads();
    if (tid < 4){
      float m = awL[tid][0];
      for (int t2=1;t2<30;++t2) m = fmaxf(m, awL[tid][t2]);
      float sum = 0.f;
      for (int t2=0;t2<30;++t2){ float e = __expf(awL[tid][t2]-m); awL[tid][t2] = e; sum += e; }
      float inv = 1.0f/sum;
      for (int t2=0;t2<30;++t2) awL[tid][t2] *= inv;
    }
    __syncthreads();
    // produce ctxv slice
    if (tid < 64){
      int b = tid >> 4, dl = tid & 15;
      float sum = 0.f;
      for (int t2=0;t2<30;++t2) sum += awL[b][t2]*(float)encOutL[b][t2][dl];
      float sn = __shfl_down(sum, 1);
      if (!(dl & 1))
        ast(CTXu + ((size_t)cur*4 + b)*512 + ((hc0 + dl) >> 1), packbf(sum, sn));
    }
    // P2: comb (blocks 0..31): poll ctxv -> LDS, K-split across 4 waves
    if (bk < 32){
      {
        const unsigned* cq = CTXu + (size_t)cur*2048 + tid*8;
        unsigned v[8];
#pragma unroll
        for (int i=0;i<8;++i) v[i] = ald(cq+i);
        bool again = true;
        while (again){ again = false;
#pragma unroll
          for (int i=0;i<8;++i) if (v[i]==SENT){ v[i] = ald(cq+i); again = true; }
        }
#pragma unroll
        for (int i=0;i<8;++i){
          int d = tid*8 + i;
          ((unsigned*)(&ctxvL[d>>9][0]))[d & 511] = v[i];
        }
      }
      __syncthreads();
      f32x4 acc = {0.f,0.f,0.f,0.f};
#pragma unroll
      for (int i = 0; i < 9; ++i){
        if (i < nkt){
          bf16x8 a = dfrag(&ctxvL[0][0], inpL, row, kt0c+i, kc, 1056);
          acc = MFMA(a, combF[i], acc);
        }
      }
      if (ln < 16){
#pragma unroll
        for (int r=0;r<4;++r) combL[w][r][ln] = acc[r];
      }
      __syncthreads();
      if (tid < 64){
        int r = tid >> 4, l = tid & 15, col = bk*16 + l;
        float x = combL[0][r][l] + combL[1][r][l] + combL[2][r][l] + combL[3][r][l] + combBias[col];
        x = fmaxf(x, 0.0f);
        float xn = __shfl_down(x, 1);
        if (!(l & 1))
          ast(XBu + ((size_t)cur*4 + r)*256 + (col >> 1), packbf(x, xn));
      }
    }
    // P3: gi gates (poll XB into regs) + gate math
    if (w < 3){
      bf16x8 xf[16];
      if (row < 4){
        const __bf16* xs2 = XB + ((size_t)cur*4 + row)*512 + kc;
#pragma unroll
        for (int kt = 0; kt < 16; ++kt) xf[kt] = ald8(xs2 + kt*32);
        bool again = true;
        while (again){ again = false;
#pragma unroll
          for (int kt = 0; kt < 16; ++kt)
            if (sent8(xf[kt])){ xf[kt] = ald8(xs2 + kt*32); again = true; }
        }
      } else {
#pragma unroll
        for (int kt = 0; kt < 16; ++kt) xf[kt] = bzero8();
      }
      f32x4 acc = {0.f,0.f,0.f,0.f};
#pragma unroll
      for (int kt = 0; kt < 16; ++kt) acc = MFMA(xf[kt], giF[kt], acc);
      if (ln < 16){
        int hcg = hc0 + ln;
        float bi = gbih[w*1024 + hcg];
        float bh = gbhh[w*1024 + hcg];
#pragma unroll
        for (int r=0;r<4;++r){
          float gi_v = acc[r] + bi;
          float gh_v = ghL[0][w][r][ln] + ghL[1][w][r][ln] + bh;
          if (w == 0) rzL[0][r][ln] = sigf(gi_v + gh_v);
          else if (w == 1) rzL[1][r][ln] = sigf(gi_v + gh_v);
          else { inL[r][ln] = gi_v; hnL[r][ln] = gh_v; }
        }
      }
    }
    __syncthreads();
    if (tid < 64){
      int b = tid >> 4, l = tid & 15, hcg = hc0 + l;
      float n = tanhf(inL[b][l] + rzL[0][b][l]*hnL[b][l]);
      float z = rzL[1][b][l];
      float hnew = (1.0f - z)*n + z*hold;
      hold = hnew;
      float h2 = __shfl_down(hnew, 1);
      if (!(l & 1))
        ast(HBu + ((size_t)nxt*4 + b)*512 + (hcg >> 1), packbf(hnew, h2));
    }
  }
}

// ---------------- host ----------------
static const size_t O_BAR   = 0;
static const size_t O_XSB   = 12288;
static const size_t O_WCATP = 1486848;
static const size_t O_BIASC = 3715072;
static const size_t O_HENC  = 3723264;
static const size_t O_CENC  = 5689344;
static const size_t O_CTX   = 9621504;
static const size_t O_WIHPF = 13553664;
static const size_t O_WIHPB = 21942272;
static const size_t O_BSUM  = 30330880;
static const size_t O_XPF   = 30347264;
static const size_t O_XPB   = 38211584;
static const size_t O_HPYR  = 46075904;
static const size_t O_OUTA  = 46108672;
static const size_t O_OUTB  = 48074752;
static const size_t O_ENCO  = 49057792;
static const size_t O_H0F   = 49549312;
static const size_t O_HB    = 49565696;
static const size_t O_CTXB  = 49598464;
static const size_t O_XB    = 49631232;
static const size_t O_ATTNP = 49647616;
static const size_t O_COMBP = 49715200;
// end 50796544 (~48.4 MiB)

extern "C" void kernel_launch(void* const* d_in, const int* in_sizes, int n_in,
                              void* d_out, int out_size, void* d_ws, size_t ws_size,
                              hipStream_t stream)
{
  const float* xs    = (const float*)d_in[0];
  const int*   xlen  = (const int*)d_in[1];
  const float* eWih  = (const float*)d_in[2];
  const float* eWhh  = (const float*)d_in[3];
  const float* ebih  = (const float*)d_in[4];
  const float* ebhh  = (const float*)d_in[5];
  const float* pWihF = (const float*)d_in[6];
  const float* pWhhF = (const float*)d_in[7];
  const float* pbihF = (const float*)d_in[8];
  const float* pbhhF = (const float*)d_in[9];
  const float* pWihB = (const float*)d_in[10];
  const float* pWhhB = (const float*)d_in[11];
  const float* pbihB = (const float*)d_in[12];
  const float* pbhhB = (const float*)d_in[13];
  const float* attnW = (const float*)d_in[14];
  const float* attnb = (const float*)d_in[15];
  const float* combW = (const float*)d_in[16];
  const float* combb = (const float*)d_in[17];
  const float* gWih  = (const float*)d_in[18];
  const float* gWhh  = (const float*)d_in[19];
  const float* gbih  = (const float*)d_in[20];
  const float* gbhh  = (const float*)d_in[21];
  const float* outW  = (const float*)d_in[22];
  const float* outb  = (const float*)d_in[23];

  char* ws = (char*)d_ws;
  unsigned* BARU  = (unsigned*)(ws + O_BAR);
  __bf16* XSB     = (__bf16*)(ws + O_XSB);
  __bf16* WCATP   = (__bf16*)(ws + O_WCATP);
  float*  BIASC   = (float*)(ws + O_BIASC);
  __bf16* HENC    = (__bf16*)(ws + O_HENC);
  float*  CENC    = (float*)(ws + O_CENC);
  __bf16* CTX     = (__bf16*)(ws + O_CTX);
  __bf16* WIHPF   = (__bf16*)(ws + O_WIHPF);
  __bf16* WIHPB   = (__bf16*)(ws + O_WIHPB);
  float*  BSUM    = (float*)(ws + O_BSUM);
  float*  XPF     = (float*)(ws + O_XPF);
  float*  XPB     = (float*)(ws + O_XPB);
  __bf16* HPYR    = (__bf16*)(ws + O_HPYR);
  __bf16* OUTA    = (__bf16*)(ws + O_OUTA);
  __bf16* OUTB    = (__bf16*)(ws + O_OUTB);
  float*  ENCO    = (float*)(ws + O_ENCO);
  float*  H0F     = (float*)(ws + O_H0F);
  __bf16* HB      = (__bf16*)(ws + O_HB);
  __bf16* CTXB    = (__bf16*)(ws + O_CTXB);
  __bf16* XB      = (__bf16*)(ws + O_XB);
  __bf16* ATTNP   = (__bf16*)(ws + O_ATTNP);
  __bf16* COMBP   = (__bf16*)(ws + O_COMBP);

  initK<<<84, 256, 0, stream>>>(BARU, (unsigned*)HB, (unsigned*)CTXB, (unsigned*)XB);
  packSmallK<<<1193, 256, 0, stream>>>(xs, eWih, eWhh, ebih, ebhh, attnW, combW,
      XSB, WCATP, BIASC, ATTNP, COMBP);

  for (int t = 0; t < 12; ++t)
    encStepK<<<dim3(30, 8), 256, 0, stream>>>(XSB, HENC, CENC, WCATP, BIASC, xlen, CTX, t);

  const int Ts[4] = {240, 120, 60, 30};
  const __bf16* ins[4] = {CTX, OUTA, OUTB, OUTA};
  __bf16* outs[4] = {OUTA, OUTB, OUTA, OUTB};
  for (int L = 0; L < 4; ++L){
    int T = Ts[L];
    packPencK<<<4113, 256, 0, stream>>>(pWihF + (long)L*2048*2048, pWihB + (long)L*2048*2048,
        pbihF + L*2048, pbhhF + L*2048, pbihB + L*2048, pbhhB + L*2048,
        WIHPF, WIHPB, BSUM);
    int MB = (4*T + 63)/64;
    pencInK<<<dim3(MB, 8, 2), 1024, 0, stream>>>(ins[L], WIHPF, WIHPB, BSUM, XPF, XPB, 4*T);
    pyrRecK<<<32, 256, 0, stream>>>(pWhhF + (long)L*2048*512, pWhhB + (long)L*2048*512,
        XPF, XPB, HPYR, outs[L], ENCO, H0F, HB,
        BARU + (size_t)(L*2+0)*256, BARU + (size_t)(L*2+1)*256, T, (L==3) ? 1 : 0);
  }

  decoderK<<<64, 256, 0, stream>>>(gWih, gWhh, gbih, gbhh, combb, attnb, outW, outb,
      ATTNP, COMBP, ENCO, H0F, HB, CTXB, XB, (float*)d_out);
}